// Round 1
// baseline (10814.163 us; speedup 1.0000x reference)
//
#include <hip/hip_runtime.h>

#define F_IN 8
#define F_OUT 16

// ---------------------------------------------------------------------------
// K1: h1 = x @ W1   (n x 8) @ (8 x 16), and deg := 1.0 (self-loop weight)
// ---------------------------------------------------------------------------
__global__ void k_h1_deginit(const float* __restrict__ x, const float* __restrict__ W1,
                             float* __restrict__ h1, float* __restrict__ deg, int n) {
    int i = blockIdx.x * blockDim.x + threadIdx.x;
    if (i >= n) return;
    const float4* xp = reinterpret_cast<const float4*>(x + (size_t)i * F_IN);
    float4 a = xp[0], b = xp[1];
    float xi[F_IN] = {a.x, a.y, a.z, a.w, b.x, b.y, b.z, b.w};
    float* hp = h1 + (size_t)i * F_OUT;
    #pragma unroll
    for (int f = 0; f < F_OUT; ++f) {
        float acc = 0.f;
        #pragma unroll
        for (int k = 0; k < F_IN; ++k) acc = fmaf(xi[k], W1[k * F_OUT + f], acc);
        hp[f] = acc;
    }
    deg[i] = 1.0f;
}

// ---------------------------------------------------------------------------
// K2: deg[col[e]] += w[e]
// ---------------------------------------------------------------------------
__global__ void k_deg(const int* __restrict__ col, const float* __restrict__ w,
                      float* __restrict__ deg, int E) {
    int e = blockIdx.x * blockDim.x + threadIdx.x;
    if (e >= E) return;
    atomicAdd(&deg[col[e]], w[e]);
}

// ---------------------------------------------------------------------------
// K3: dinv = deg > 0 ? rsqrt(deg) : 0
// ---------------------------------------------------------------------------
__global__ void k_dinv(const float* __restrict__ deg, float* __restrict__ dinv, int n) {
    int i = blockIdx.x * blockDim.x + threadIdx.x;
    if (i >= n) return;
    float d = deg[i];
    dinv[i] = d > 0.f ? rsqrtf(d) : 0.f;
}

// ---------------------------------------------------------------------------
// K4/K6-part: out[i] = h[i] * dinv[i]^2 + bias   (self-loop + bias init)
// ---------------------------------------------------------------------------
__global__ void k_init_out(const float* __restrict__ h, const float* __restrict__ dinv,
                           const float* __restrict__ bias, float* __restrict__ out, int n) {
    int i = blockIdx.x * blockDim.x + threadIdx.x;
    if (i >= n) return;
    float s = dinv[i] * dinv[i];
    const float4* hp = reinterpret_cast<const float4*>(h + (size_t)i * F_OUT);
    float4* op = reinterpret_cast<float4*>(out + (size_t)i * F_OUT);
    #pragma unroll
    for (int q = 0; q < 4; ++q) {
        float4 v = hp[q];
        float4 bq = reinterpret_cast<const float4*>(bias)[q];
        v.x = fmaf(v.x, s, bq.x);
        v.y = fmaf(v.y, s, bq.y);
        v.z = fmaf(v.z, s, bq.z);
        v.w = fmaf(v.w, s, bq.w);
        op[q] = v;
    }
}

// ---------------------------------------------------------------------------
// K5/K7: edge scatter: out[col] += h[row] * (dinv[row]*w*dinv[col])
// ---------------------------------------------------------------------------
__global__ void k_scatter(const int* __restrict__ row, const int* __restrict__ col,
                          const float* __restrict__ w, const float* __restrict__ dinv,
                          const float* __restrict__ h, float* __restrict__ out, int E) {
    int e = blockIdx.x * blockDim.x + threadIdx.x;
    if (e >= E) return;
    int r = row[e];
    int c = col[e];
    float norm = dinv[r] * w[e] * dinv[c];
    const float4* hp = reinterpret_cast<const float4*>(h + (size_t)r * F_OUT);
    float* op = out + (size_t)c * F_OUT;
    #pragma unroll
    for (int q = 0; q < 4; ++q) {
        float4 v = hp[q];
        atomicAdd(op + q * 4 + 0, v.x * norm);
        atomicAdd(op + q * 4 + 1, v.y * norm);
        atomicAdd(op + q * 4 + 2, v.z * norm);
        atomicAdd(op + q * 4 + 3, v.w * norm);
    }
}

// ---------------------------------------------------------------------------
// K6: h2 = relu(out1) @ W2, and out_init = h2 * dinv^2 + b2
// ---------------------------------------------------------------------------
__global__ void k_h2_init(const float* __restrict__ out1, const float* __restrict__ W2,
                          const float* __restrict__ b2, const float* __restrict__ dinv,
                          float* __restrict__ h2, float* __restrict__ out, int n) {
    int i = blockIdx.x * blockDim.x + threadIdx.x;
    if (i >= n) return;
    float hi[F_OUT];
    const float4* ip = reinterpret_cast<const float4*>(out1 + (size_t)i * F_OUT);
    #pragma unroll
    for (int q = 0; q < 4; ++q) {
        float4 v = ip[q];
        hi[q * 4 + 0] = fmaxf(v.x, 0.f);
        hi[q * 4 + 1] = fmaxf(v.y, 0.f);
        hi[q * 4 + 2] = fmaxf(v.z, 0.f);
        hi[q * 4 + 3] = fmaxf(v.w, 0.f);
    }
    float s = dinv[i] * dinv[i];
    float* h2p = h2 + (size_t)i * F_OUT;
    float* op = out + (size_t)i * F_OUT;
    #pragma unroll
    for (int f = 0; f < F_OUT; ++f) {
        float acc = 0.f;
        #pragma unroll
        for (int k = 0; k < F_OUT; ++k) acc = fmaf(hi[k], W2[k * F_OUT + f], acc);
        h2p[f] = acc;
        op[f] = fmaf(acc, s, b2[f]);
    }
}

extern "C" void kernel_launch(void* const* d_in, const int* in_sizes, int n_in,
                              void* d_out, int out_size, void* d_ws, size_t ws_size,
                              hipStream_t stream) {
    const float* x  = (const float*)d_in[0];
    const int*   ei = (const int*)d_in[1];   // int32 (JAX x64 disabled)
    const float* w  = (const float*)d_in[2];
    const float* W1 = (const float*)d_in[3];
    const float* b1 = (const float*)d_in[4];
    const float* W2 = (const float*)d_in[5];
    const float* b2 = (const float*)d_in[6];
    float* out = (float*)d_out;

    const int n = in_sizes[0] / F_IN;        // 100000
    const int E = in_sizes[2];               // 6400000
    const int* row = ei;
    const int* col = ei + E;

    // Workspace layout (floats): deg[n] | dinv[n] | h1[16n] (reused as h2) | out1[16n]
    float* ws   = (float*)d_ws;
    float* deg  = ws;
    float* dinv = ws + n;
    float* h1   = ws + 2 * (size_t)n;        // also h2 later
    float* out1 = ws + 2 * (size_t)n + 16 * (size_t)n;

    const int B = 256;
    const int gn  = (n + B - 1) / B;
    const int gE  = (E + B - 1) / B;

    // Layer 1
    k_h1_deginit<<<gn, B, 0, stream>>>(x, W1, h1, deg, n);
    k_deg<<<gE, B, 0, stream>>>(col, w, deg, E);
    k_dinv<<<gn, B, 0, stream>>>(deg, dinv, n);
    k_init_out<<<gn, B, 0, stream>>>(h1, dinv, b1, out1, n);
    k_scatter<<<gE, B, 0, stream>>>(row, col, w, dinv, h1, out1, E);

    // Layer 2 (h2 reuses h1 slot; out init fused)
    k_h2_init<<<gn, B, 0, stream>>>(out1, W2, b2, dinv, h1, out, n);
    k_scatter<<<gE, B, 0, stream>>>(row, col, w, dinv, h1, out, E);
}

// Round 3
// 1203.440 us; speedup vs baseline: 8.9860x; 8.9860x over previous
//
#include <hip/hip_runtime.h>

#define NF 16   // feature width of h / output
#define FI 8    // input feature width
#define SCAN_T 256
#define SCAN_I 4        // 1024 elements per scan block

// ---------------------------------------------------------------------------
// shared: h1 = x @ W1   (n x 8) @ (8 x 16)
// ---------------------------------------------------------------------------
__global__ void k_h1(const float* __restrict__ x, const float* __restrict__ W1,
                     float* __restrict__ h, int n) {
    int i = blockIdx.x * blockDim.x + threadIdx.x;
    if (i >= n) return;
    const float4* xp = reinterpret_cast<const float4*>(x + (size_t)i * FI);
    float4 a = xp[0], b = xp[1];
    float xi[FI] = {a.x, a.y, a.z, a.w, b.x, b.y, b.z, b.w};
    float* hp = h + (size_t)i * NF;
    #pragma unroll
    for (int f = 0; f < NF; ++f) {
        float acc = 0.f;
        #pragma unroll
        for (int k = 0; k < FI; ++k) acc = fmaf(xi[k], W1[k * NF + f], acc);
        hp[f] = acc;
    }
}

// shared: deg := 1 (self-loop)
__global__ void k_deg_init(float* __restrict__ deg, int n) {
    int i = blockIdx.x * blockDim.x + threadIdx.x;
    if (i < n) deg[i] = 1.0f;
}

// shared: deg[col[e]] += w[e]
__global__ void k_deg_acc(const int* __restrict__ col, const float* __restrict__ w,
                          float* __restrict__ deg, int E) {
    int e = blockIdx.x * blockDim.x + threadIdx.x;
    if (e < E) atomicAdd(&deg[col[e]], w[e]);
}

// shared: dinv = rsqrt(deg) in place (deg >= 1 always)
__global__ void k_dinv_ip(float* __restrict__ d, int n) {
    int i = blockIdx.x * blockDim.x + threadIdx.x;
    if (i < n) d[i] = rsqrtf(d[i]);
}

// shared: h2 = relu(out1) @ W2
__global__ void k_h2(const float* __restrict__ out1, const float* __restrict__ W2,
                     float* __restrict__ h2, int n) {
    int i = blockIdx.x * blockDim.x + threadIdx.x;
    if (i >= n) return;
    float hi[NF];
    const float4* ip = reinterpret_cast<const float4*>(out1 + (size_t)i * NF);
    #pragma unroll
    for (int q = 0; q < 4; ++q) {
        float4 v = ip[q];
        hi[q * 4 + 0] = fmaxf(v.x, 0.f);
        hi[q * 4 + 1] = fmaxf(v.y, 0.f);
        hi[q * 4 + 2] = fmaxf(v.z, 0.f);
        hi[q * 4 + 3] = fmaxf(v.w, 0.f);
    }
    float* hp = h2 + (size_t)i * NF;
    #pragma unroll
    for (int f = 0; f < NF; ++f) {
        float acc = 0.f;
        #pragma unroll
        for (int k = 0; k < NF; ++k) acc = fmaf(hi[k], W2[k * NF + f], acc);
        hp[f] = acc;
    }
}

// ======================== CSR (gather) path ================================

__global__ void k_hist(const int* __restrict__ col, int* __restrict__ cnt, int E) {
    int e = blockIdx.x * blockDim.x + threadIdx.x;
    if (e < E) atomicAdd(&cnt[col[e]], 1);
}

__global__ void k_scanA(const int* __restrict__ cnt, int* __restrict__ offs,
                        int* __restrict__ bsum, int n) {
    __shared__ int lds[SCAN_T];
    int t = threadIdx.x;
    int base = blockIdx.x * (SCAN_T * SCAN_I) + t * SCAN_I;
    int v[SCAN_I];
    int s = 0;
    #pragma unroll
    for (int j = 0; j < SCAN_I; ++j) {
        int i = base + j;
        v[j] = (i < n) ? cnt[i] : 0;
        s += v[j];
    }
    lds[t] = s;
    __syncthreads();
    for (int d = 1; d < SCAN_T; d <<= 1) {
        int add = (t >= d) ? lds[t - d] : 0;
        __syncthreads();
        lds[t] += add;
        __syncthreads();
    }
    if (t == SCAN_T - 1) bsum[blockIdx.x] = lds[t];
    int run = t ? lds[t - 1] : 0;
    #pragma unroll
    for (int j = 0; j < SCAN_I; ++j) {
        int i = base + j;
        if (i < n) offs[i] = run;
        run += v[j];
    }
}

__global__ void k_scanB(const int* __restrict__ bsum, int* __restrict__ bpre, int nb) {
    __shared__ int lds[256];
    int t = threadIdx.x;
    int v = (t < nb) ? bsum[t] : 0;
    lds[t] = v;
    __syncthreads();
    for (int d = 1; d < 256; d <<= 1) {
        int add = (t >= d) ? lds[t - d] : 0;
        __syncthreads();
        lds[t] += add;
        __syncthreads();
    }
    if (t < nb) bpre[t] = lds[t] - v;  // exclusive
}

// sorted[start(c)+cur[c]++] = {row[e], dinv[row[e]]*w[e]}
__global__ void k_build(const int* __restrict__ row, const int* __restrict__ col,
                        const float* __restrict__ w, const float* __restrict__ dinv,
                        const int* __restrict__ offs, const int* __restrict__ bpre,
                        int* __restrict__ cur, float2* __restrict__ sorted, int E) {
    int e = blockIdx.x * blockDim.x + threadIdx.x;
    if (e >= E) return;
    int c = col[e];
    int r = row[e];
    int p = offs[c] + bpre[c >> 10] + atomicAdd(&cur[c], 1);
    float2 pr;
    pr.x = __int_as_float(r);
    pr.y = dinv[r] * w[e];
    sorted[p] = pr;
}

// one wave per destination node; 4 edge-subgroups x 16 features
__global__ void k_gather(const float2* __restrict__ sorted, const int* __restrict__ offs,
                         const int* __restrict__ bpre, const float* __restrict__ dinv,
                         const float* __restrict__ h, const float* __restrict__ bias,
                         float* __restrict__ out, int n, int E) {
    int wid = (int)((blockIdx.x * blockDim.x + threadIdx.x) >> 6);
    if (wid >= n) return;
    int lane = threadIdx.x & 63;
    int sub = lane >> 4, f = lane & 15;
    int s = offs[wid] + bpre[wid >> 10];
    int epos = (wid + 1 < n) ? offs[wid + 1] + bpre[(wid + 1) >> 10] : E;
    float acc = 0.f;
    for (int e = s + sub; e < epos; e += 4) {
        float2 pr = sorted[e];
        int r = __float_as_int(pr.x);
        acc = fmaf(h[r * NF + f], pr.y, acc);
    }
    acc += __shfl_xor(acc, 16);
    acc += __shfl_xor(acc, 32);
    if (sub == 0) {
        float dc = dinv[wid];
        float self = h[wid * NF + f];
        out[wid * NF + f] = fmaf(dc, acc, fmaf(dc * dc, self, bias[f]));
    }
}

// ======================== fallback (atomic scatter) path ===================

__global__ void k_init_out(const float* __restrict__ h, const float* __restrict__ dinv,
                           const float* __restrict__ bias, float* __restrict__ out, int n) {
    int i = blockIdx.x * blockDim.x + threadIdx.x;
    if (i >= n) return;
    float s = dinv[i] * dinv[i];
    const float4* hp = reinterpret_cast<const float4*>(h + (size_t)i * NF);
    float4* op = reinterpret_cast<float4*>(out + (size_t)i * NF);
    #pragma unroll
    for (int q = 0; q < 4; ++q) {
        float4 v = hp[q];
        float4 bq = reinterpret_cast<const float4*>(bias)[q];
        v.x = fmaf(v.x, s, bq.x);
        v.y = fmaf(v.y, s, bq.y);
        v.z = fmaf(v.z, s, bq.z);
        v.w = fmaf(v.w, s, bq.w);
        op[q] = v;
    }
}

__global__ void k_scatter(const int* __restrict__ row, const int* __restrict__ col,
                          const float* __restrict__ w, const float* __restrict__ dinv,
                          const float* __restrict__ h, float* __restrict__ out, int E) {
    int e = blockIdx.x * blockDim.x + threadIdx.x;
    if (e >= E) return;
    int r = row[e];
    int c = col[e];
    float norm = dinv[r] * w[e] * dinv[c];
    const float4* hp = reinterpret_cast<const float4*>(h + (size_t)r * NF);
    float* op = out + (size_t)c * NF;
    #pragma unroll
    for (int q = 0; q < 4; ++q) {
        float4 v = hp[q];
        atomicAdd(op + q * 4 + 0, v.x * norm);
        atomicAdd(op + q * 4 + 1, v.y * norm);
        atomicAdd(op + q * 4 + 2, v.z * norm);
        atomicAdd(op + q * 4 + 3, v.w * norm);
    }
}

// ===========================================================================

extern "C" void kernel_launch(void* const* d_in, const int* in_sizes, int n_in,
                              void* d_out, int out_size, void* d_ws, size_t ws_size,
                              hipStream_t stream) {
    const float* x  = (const float*)d_in[0];
    const int*   ei = (const int*)d_in[1];   // int32 (verified: round 1 passed)
    const float* w  = (const float*)d_in[2];
    const float* W1 = (const float*)d_in[3];
    const float* b1 = (const float*)d_in[4];
    const float* W2 = (const float*)d_in[5];
    const float* b2 = (const float*)d_in[6];
    float* out = (float*)d_out;

    const int n = in_sizes[0] / FI;          // 100000
    const int E = in_sizes[2];               // 6400000
    const int* row = ei;
    const int* col = ei + E;

    const int B = 256;
    const int gn = (n + B - 1) / B;
    const int gE = (E + B - 1) / B;
    const int NB1 = (n + SCAN_T * SCAN_I - 1) / (SCAN_T * SCAN_I);  // 98

    // CSR-path workspace (floats): sorted(2E) | cnt(n) | offs(n) | scan(512) |
    //                              dinv(n) | h(16n) | out1(16n)
    size_t csr_need = ((size_t)2 * E + 35 * (size_t)n + 512) * 4;
    bool use_csr = (ws_size >= csr_need) && (NB1 <= 256);

    if (use_csr) {
        float*  ws     = (float*)d_ws;
        float2* sorted = (float2*)ws;
        int*    cnt    = (int*)(ws + 2 * (size_t)E);
        int*    offs   = cnt + n;
        int*    bsum   = offs + n;
        int*    bpre   = bsum + 256;
        float*  dinv   = (float*)(bpre + 256);
        float*  h      = dinv + n;                 // h1, later h2
        float*  out1   = h + 16 * (size_t)n;

        hipMemsetAsync(cnt, 0, (size_t)n * 4, stream);
        k_h1<<<gn, B, 0, stream>>>(x, W1, h, n);
        k_deg_init<<<gn, B, 0, stream>>>(dinv, n);
        k_deg_acc<<<gE, B, 0, stream>>>(col, w, dinv, E);
        k_dinv_ip<<<gn, B, 0, stream>>>(dinv, n);
        k_hist<<<gE, B, 0, stream>>>(col, cnt, E);
        k_scanA<<<NB1, SCAN_T, 0, stream>>>(cnt, offs, bsum, n);
        k_scanB<<<1, 256, 0, stream>>>(bsum, bpre, NB1);
        hipMemsetAsync(cnt, 0, (size_t)n * 4, stream);   // reuse as cursors
        k_build<<<gE, B, 0, stream>>>(row, col, w, dinv, offs, bpre, cnt, sorted, E);

        k_gather<<<(n * 64 + B - 1) / B, B, 0, stream>>>(sorted, offs, bpre, dinv, h, b1, out1, n, E);
        k_h2<<<gn, B, 0, stream>>>(out1, W2, h, n);
        k_gather<<<(n * 64 + B - 1) / B, B, 0, stream>>>(sorted, offs, bpre, dinv, h, b2, out, n, E);
    } else {
        // fallback: round-1 structure (13.2 MB ws), passed at 10.8 ms
        float* ws   = (float*)d_ws;
        float* dinv = ws;
        float* h    = ws + (size_t)n;
        float* out1 = h + 16 * (size_t)n;

        k_h1<<<gn, B, 0, stream>>>(x, W1, h, n);
        k_deg_init<<<gn, B, 0, stream>>>(dinv, n);
        k_deg_acc<<<gE, B, 0, stream>>>(col, w, dinv, E);
        k_dinv_ip<<<gn, B, 0, stream>>>(dinv, n);
        k_init_out<<<gn, B, 0, stream>>>(h, dinv, b1, out1, n);
        k_scatter<<<gE, B, 0, stream>>>(row, col, w, dinv, h, out1, E);
        k_h2<<<gn, B, 0, stream>>>(out1, W2, h, n);
        k_init_out<<<gn, B, 0, stream>>>(h, dinv, b2, out, n);
        k_scatter<<<gE, B, 0, stream>>>(row, col, w, dinv, h, out, E);
    }
}